// Round 6
// baseline (153.025 us; speedup 1.0000x reference)
//
#include <hip/hip_runtime.h>
#include <hip/hip_bf16.h>
#include <math.h>

#define B_ 2
#define N_ 4096          // H*W*D
#define BN_ 8192
#define NH_ 4
#define SPLIT_ 8         // attention K-split (in-block: 8 waves = 8 splits)

using bf16x8   = __attribute__((ext_vector_type(8))) __bf16;
using f32x4    = __attribute__((ext_vector_type(4))) float;
using ushortx8 = __attribute__((ext_vector_type(8))) unsigned short;

#if __has_builtin(__builtin_amdgcn_exp2f)
#define FAST_EXP2(x) __builtin_amdgcn_exp2f(x)
#else
#define FAST_EXP2(x) __expf((x) * 0.6931471805599453f)
#endif

static __device__ __forceinline__ unsigned short f2bf(float f) {
    union { __hip_bfloat16 h; unsigned short u; } c;
    c.h = __float2bfloat16(f);
    return c.u;
}
static __device__ __forceinline__ float bf2f(unsigned short u) {
    union { __hip_bfloat16 h; unsigned short u; } c;
    c.u = u;
    return __bfloat162float(c.h);
}
// pack two f32 -> two bf16 (round-biased truncate) in one v_perm_b32
static __device__ __forceinline__ unsigned int pk2bf(float lo, float hi) {
    return __builtin_amdgcn_perm(__float_as_uint(hi) + 0x8000u,
                                 __float_as_uint(lo) + 0x8000u, 0x07060302u);
}

// ---------------------------------------------------------------------------
// QKV v6 (R2-proven, unchanged): LDS-staged LN + projection with LDS-staged
// bf16 weights; float4 input staging; tail-weight conversion folded into the
// 768 main blocks (grid 768 = exactly 3 blocks/CU, single-shot).
// ---------------------------------------------------------------------------
__global__ __launch_bounds__(256)
void qkv4_kernel(const float* __restrict__ enc, const float* __restrict__ dec,
                 const float* __restrict__ g_enc, const float* __restrict__ b_enc,
                 const float* __restrict__ g_dec, const float* __restrict__ b_dec,
                 const float* __restrict__ Wq, const float* __restrict__ Wk,
                 const float* __restrict__ Wv,
                 const float* __restrict__ bq, const float* __restrict__ bk,
                 const float* __restrict__ bv,
                 const float* __restrict__ Wo, const float* __restrict__ W1,
                 const float* __restrict__ W2,
                 unsigned short* __restrict__ wo, unsigned short* __restrict__ w1,
                 unsigned short* __restrict__ w2,
                 unsigned short* __restrict__ Qh, unsigned short* __restrict__ Kh,
                 unsigned short* __restrict__ Vt,
                 unsigned short* __restrict__ dec_lnb) {
    const int t = threadIdx.x;
    __shared__ float tile[128][33];
    __shared__ float mu_s[32], inv_s[32];
    __shared__ alignas(16) unsigned short Wlds[128][136];   // 34.8 KB, pad=8
    const int z  = blockIdx.x >> 8;       // 0 Q/dec, 1 K/enc, 2 V/enc
    const int m0 = (blockIdx.x & 255) * 32;
    const int b  = m0 >> 12, n0 = m0 & 4095;
    const float* inb   = ((z == 0) ? dec : enc) + (size_t)b * 128 * N_;
    const float* gamma = (z == 0) ? g_dec : g_enc;
    const float* beta  = (z == 0) ? b_dec : b_enc;
    const float* Wb    = (z == 0) ? Wq : ((z == 1) ? Wk : Wv);

    // ---- folded tail-weight conversion: 192 elems per block (24 thr x 8)
    if (t < 24) {
        const int e = (int)blockIdx.x * 192 + t * 8;
        const float* src; unsigned short* dst; int off;
        if (e < 16384)       { src = Wo; dst = wo; off = e; }
        else if (e < 81920)  { src = W1; dst = w1; off = e - 16384; }
        else                 { src = W2; dst = w2; off = e - 81920; }
        const float4 a = *(const float4*)(src + off);
        const float4 bq4 = *(const float4*)(src + off + 4);
        uint4 p;
        p.x = pk2bf(a.x, a.y); p.y = pk2bf(a.z, a.w);
        p.z = pk2bf(bq4.x, bq4.y); p.w = pk2bf(bq4.z, bq4.w);
        *(uint4*)(dst + off) = p;
    }

    // stage input: 128 chans x 32 tokens, float4 global loads (coalesced)
    {
        const int r0 = t >> 3;            // 0..31
        const int cf = (t & 7) * 4;
        #pragma unroll
        for (int j = 0; j < 4; ++j) {
            const int r = r0 + 32 * j;
            const float4 x = *(const float4*)(inb + (size_t)r * N_ + n0 + cf);
            tile[r][cf]     = x.x; tile[r][cf + 1] = x.y;
            tile[r][cf + 2] = x.z; tile[r][cf + 3] = x.w;
        }
    }
    // stage + convert weights: 128x128 fp32 -> bf16 LDS, coalesced (2KB/instr)
    {
        #pragma unroll
        for (int i = 0; i < 8; ++i) {
            const int e   = (i * 256 + t) * 8;    // linear element, row-major [col][k]
            const int col = e >> 7, k = e & 127;
            const float4 wa = *(const float4*)(Wb + e);
            const float4 wb = *(const float4*)(Wb + e + 4);
            uint4 p;
            p.x = pk2bf(wa.x, wa.y); p.y = pk2bf(wa.z, wa.w);
            p.z = pk2bf(wb.x, wb.y); p.w = pk2bf(wb.z, wb.w);
            *(uint4*)&Wlds[col][k] = p;
        }
    }
    __syncthreads();
    // LN stats: 8 threads per token
    {
        const int tok = t >> 3;
        const int ln  = t & 7;
        float s = 0.f, ss = 0.f;
        for (int c = ln; c < 128; c += 8) {
            const float x = tile[c][tok];
            s += x; ss += x * x;
        }
        for (int m = 1; m < 8; m <<= 1) {
            s  += __shfl_xor(s, m);
            ss += __shfl_xor(ss, m);
        }
        if (ln == 0) {
            const float mu  = s * (1.f / 128.f);
            mu_s[tok]  = mu;
            inv_s[tok] = rsqrtf(ss * (1.f / 128.f) - mu * mu + 1e-5f);
        }
    }
    __syncthreads();

    const int wvx = t >> 6, lane = t & 63;
    const int l15 = lane & 15, quad = lane >> 4;
    const int tokgrp  = (wvx & 1) * 16;
    const int colbase = (wvx >> 1) * 64;
    const bool wrLN   = (z == 0) && ((wvx >> 1) == 0);
    const int tok = tokgrp + l15;
    const float mu  = mu_s[tok];
    const float inv = inv_s[tok];

    // build LN'd A-frags straight from LDS
    bf16x8 af[4];
    #pragma unroll
    for (int kk = 0; kk < 4; ++kk) {
        float y[8];
        #pragma unroll
        for (int j = 0; j < 8; ++j) {
            const int c = kk * 32 + quad * 8 + j;
            y[j] = (tile[c][tok] - mu) * inv * gamma[c] + beta[c];
        }
        union { uint4 u; bf16x8 v8; ushortx8 us; } cvt;
        cvt.u.x = pk2bf(y[0], y[1]); cvt.u.y = pk2bf(y[2], y[3]);
        cvt.u.z = pk2bf(y[4], y[5]); cvt.u.w = pk2bf(y[6], y[7]);
        af[kk] = cvt.v8;
        if (wrLN)
            *(ushortx8*)(dec_lnb + (size_t)(m0 + tok) * 128 + kk * 32 + quad * 8) = cvt.us;
    }

    const float* bias = (z == 0) ? bq : ((z == 1) ? bk : bv);
    const float sc = (z == 0) ? (0.17677669529663687f * 1.4426950408889634f) : 1.f;
    const int nbase = n0 + tokgrp + quad * 4;

    #pragma unroll
    for (int nb = 0; nb < 4; ++nb) {
        const int col = colbase + nb * 16 + l15;
        f32x4 a = {0.f, 0.f, 0.f, 0.f};
        #pragma unroll
        for (int kk = 0; kk < 4; ++kk) {
            const bf16x8 wf = *(const bf16x8*)&Wlds[col][kk * 32 + quad * 8];
            a = __builtin_amdgcn_mfma_f32_16x16x32_bf16(af[kk], wf, a, 0, 0, 0);
        }
        const int h = col >> 5, d = col & 31;
        const float bz = bias[col];
        if (z == 2) {
            ushort4 pk;
            pk.x = f2bf(a[0] + bz);
            pk.y = f2bf(a[1] + bz);
            pk.z = f2bf(a[2] + bz);
            pk.w = f2bf(a[3] + bz);
            *(ushort4*)(Vt + ((size_t)(b * NH_ + h) * 32 + d) * N_ + nbase) = pk;
        } else {
            unsigned short* dst = (z == 0) ? Qh : Kh;
            #pragma unroll
            for (int r = 0; r < 4; ++r)
                dst[((size_t)(b * NH_ + h) * N_ + nbase + r) * 32 + d] = f2bf((a[r] + bz) * sc);
        }
    }
}

// ---------------------------------------------------------------------------
// Attention v11 (R5-proven, unchanged): register diet (no kfn prefetch),
// __launch_bounds__(512, 2) = 2 blocks/CU (hipcc CUDA-style semantics,
// calibrated via R3: (512,4) forced VGPR=64) -> VGPR <= 128, 4 waves/SIMD.
// ---------------------------------------------------------------------------
__global__ __launch_bounds__(512, 2)
void attn_kernel7(const unsigned short* __restrict__ Qh,
                  const unsigned short* __restrict__ Kh,
                  const unsigned short* __restrict__ Vt,
                  unsigned short* __restrict__ ctx) {
    __shared__ alignas(16) unsigned short sP[8][64][72];  // 73728 B; reused fp32 [8][64][36]
    __shared__ float ldsL[8][64];

    const int gid  = blockIdx.x;
    const int bh   = gid & 7;
    const int qblk = gid >> 3;          // 0..63
    const int t  = threadIdx.x;
    const int wvx = t >> 6, lane = t & 63;
    const int l15 = lane & 15, quad = lane >> 4;
    const int s = wvx;
    const int qw = qblk * 64;
    const size_t hbse = (size_t)bh * N_ * 32;

    bf16x8 qf[4];
    #pragma unroll
    for (int f = 0; f < 4; ++f)
        qf[f] = *(const bf16x8*)(Qh + hbse + (size_t)(qw + f * 16 + l15) * 32 + quad * 8);

    const unsigned short* Kp = Kh + hbse;
    const unsigned short* Vp = Vt + (size_t)bh * 32 * N_;

    f32x4 o0[4], o1[4];
    float l[4];
    #pragma unroll
    for (int f = 0; f < 4; ++f) {
        o0[f] = f32x4{0.f, 0.f, 0.f, 0.f};
        o1[f] = f32x4{0.f, 0.f, 0.f, 0.f};
        l[f] = 0.f;
    }
    const f32x4 zero = {0.f, 0.f, 0.f, 0.f};

    const int kbeg = s * (N_ / SPLIT_);
    const int kend = kbeg + (N_ / SPLIT_);

    for (int k0 = kbeg; k0 < kend; k0 += 64) {
        // K fragments for THIS iter (no cross-iter prefetch: register diet)
        bf16x8 kf[4];
        #pragma unroll
        for (int c = 0; c < 4; ++c)
            kf[c] = *(const bf16x8*)(Kp + (size_t)(k0 + c * 16 + l15) * 32 + quad * 8);
        bf16x8 va[2], vb[2];
        #pragma unroll
        for (int s2 = 0; s2 < 2; ++s2) {
            va[s2] = *(const bf16x8*)(Vp + (size_t)l15 * N_        + k0 + s2 * 32 + quad * 8);
            vb[s2] = *(const bf16x8*)(Vp + (size_t)(16 + l15) * N_ + k0 + s2 * 32 + quad * 8);
        }

        __builtin_amdgcn_s_setprio(1);
        #pragma unroll
        for (int f = 0; f < 4; ++f) {
            #pragma unroll
            for (int c = 0; c < 4; ++c) {
                const f32x4 sv = __builtin_amdgcn_mfma_f32_16x16x32_bf16(kf[c], qf[f], zero, 0, 0, 0);
                const float p0 = FAST_EXP2(sv[0]);
                const float p1 = FAST_EXP2(sv[1]);
                const float p2 = FAST_EXP2(sv[2]);
                const float p3 = FAST_EXP2(sv[3]);
                l[f] += (p0 + p1) + (p2 + p3);
                uint2 pk;
                pk.x = pk2bf(p0, p1);
                pk.y = pk2bf(p2, p3);
                *(uint2*)&sP[wvx][f * 16 + l15][c * 16 + quad * 4] = pk;
            }
        }
        __builtin_amdgcn_s_setprio(0);
        __builtin_amdgcn_s_setprio(1);
        #pragma unroll
        for (int f = 0; f < 4; ++f) {
            #pragma unroll
            for (int s2 = 0; s2 < 2; ++s2) {
                const bf16x8 pf = *(const bf16x8*)&sP[wvx][f * 16 + l15][s2 * 32 + quad * 8];
                o0[f] = __builtin_amdgcn_mfma_f32_16x16x32_bf16(va[s2], pf, o0[f], 0, 0, 0);
                o1[f] = __builtin_amdgcn_mfma_f32_16x16x32_bf16(vb[s2], pf, o1[f], 0, 0, 0);
            }
        }
        __builtin_amdgcn_s_setprio(0);
    }

    float lf4[4];
    #pragma unroll
    for (int f = 0; f < 4; ++f) {
        float lf = l[f];
        lf += __shfl_xor(lf, 16);
        lf += __shfl_xor(lf, 32);
        lf4[f] = lf;
    }

    __syncthreads();
    float* ldsO = (float*)&sP[0][0][0];   // [8][64][36]
    #pragma unroll
    for (int f = 0; f < 4; ++f) {
        const int q = f * 16 + l15;
        float* row = ldsO + ((size_t)s * 64 + q) * 36;
        *(f32x4*)(row + quad * 4)      = o0[f];
        *(f32x4*)(row + 16 + quad * 4) = o1[f];
        if (quad == 0) ldsL[s][q] = lf4[f];
    }
    __syncthreads();

    const int tok = t >> 3;
    const int d0  = (t & 7) * 4;
    f32x4 sum = {0.f, 0.f, 0.f, 0.f};
    float lsum = 0.f;
    #pragma unroll
    for (int w = 0; w < 8; ++w) {
        sum  += *(const f32x4*)(ldsO + ((size_t)w * 64 + tok) * 36 + d0);
        lsum += ldsL[w][tok];
    }
    const float inv = 1.f / lsum;
    uint2 pk;
    pk.x = pk2bf(sum[0] * inv, sum[1] * inv);
    pk.y = pk2bf(sum[2] * inv, sum[3] * inv);
    const int b = bh >> 2, h = bh & 3;
    *(uint2*)(ctx + ((size_t)(b * N_ + qw + tok)) * 128 + h * 32 + d0) = pk;
}

// ---------------------------------------------------------------------------
// Fused tail v7: 512 threads / 8 waves per block (was 256/4) -> occupancy
// doubles to 4 waves/SIMD (2 blocks/CU x 16 waves). Wave wv owns ONE 16-col
// output group (Wo 4 MFMA, FFN2 16 MFMA full-K) and a 64-col FFN1 slice
// (16 MFMA). Same total MFMA per block (288); per-wave VGPR halves; LDS
// unchanged (~22 KB). erf/w1/w2 latencies now hidden by 4-deep TLP.
// ---------------------------------------------------------------------------
__global__ __launch_bounds__(512)
void fused_tail7_kernel(const unsigned short* __restrict__ ctx,
                        const unsigned short* __restrict__ wo,
                        const float* __restrict__ bo,
                        const unsigned short* __restrict__ decb,
                        const float* __restrict__ g, const float* __restrict__ be,
                        const unsigned short* __restrict__ w1,
                        const float* __restrict__ b1,
                        const unsigned short* __restrict__ w2,
                        const float* __restrict__ b2,
                        float* __restrict__ out) {
    __shared__ float sln[8][2][16];
    __shared__ alignas(16) unsigned short hb_lds[16][136];
    __shared__ alignas(16) unsigned short smid[16][536];
    const int t = threadIdx.x;
    const int wv = t >> 6, lane = t & 63;
    const int l15 = lane & 15, quad = lane >> 4;
    const int m0 = blockIdx.x * 16;
    const int col = wv * 16 + l15;          // this wave's output column

    // ---- A-frags: ALL 128 chans of token m0+l15 (4 x 16B loads)
    bf16x8 af[4];
    #pragma unroll
    for (int kk = 0; kk < 4; ++kk)
        af[kk] = *(const bf16x8*)(ctx + (size_t)(m0 + l15) * 128 + kk * 32 + quad * 8);

    // ---- Wo FULL-K (K=128): 4 MFMA, 2 independent chains
    float v[4];
    {
        f32x4 a0 = {0.f, 0.f, 0.f, 0.f};
        f32x4 a1 = {0.f, 0.f, 0.f, 0.f};
        const bf16x8 w0 = *(const bf16x8*)(wo + (size_t)col * 128 + 0 * 32 + quad * 8);
        const bf16x8 w1f = *(const bf16x8*)(wo + (size_t)col * 128 + 1 * 32 + quad * 8);
        const bf16x8 w2f = *(const bf16x8*)(wo + (size_t)col * 128 + 2 * 32 + quad * 8);
        const bf16x8 w3f = *(const bf16x8*)(wo + (size_t)col * 128 + 3 * 32 + quad * 8);
        a0 = __builtin_amdgcn_mfma_f32_16x16x32_bf16(af[0], w0,  a0, 0, 0, 0);
        a1 = __builtin_amdgcn_mfma_f32_16x16x32_bf16(af[1], w1f, a1, 0, 0, 0);
        a0 = __builtin_amdgcn_mfma_f32_16x16x32_bf16(af[2], w2f, a0, 0, 0, 0);
        a1 = __builtin_amdgcn_mfma_f32_16x16x32_bf16(af[3], w3f, a1, 0, 0, 0);
        const f32x4 a = a0 + a1;
        const float bz = bo[col];
        #pragma unroll
        for (int r = 0; r < 4; ++r) {
            const int tok = m0 + quad * 4 + r;
            v[r] = a[r] + bz + bf2f(decb[(size_t)tok * 128 + col]);
        }
    }

    // ---- LN partial sums over this wave's 16 cols
    {
        float s[4], ss[4];
        #pragma unroll
        for (int r = 0; r < 4; ++r) {
            float a = v[r];
            float b = v[r] * v[r];
            for (int m = 1; m < 16; m <<= 1) {
                a += __shfl_xor(a, m);
                b += __shfl_xor(b, m);
            }
            s[r] = a; ss[r] = b;
        }
        if (l15 == 0) {
            #pragma unroll
            for (int r = 0; r < 4; ++r) {
                sln[wv][0][quad * 4 + r] = s[r];
                sln[wv][1][quad * 4 + r] = ss[r];
            }
        }
    }
    __syncthreads();

    // ---- full LN stats (sum 8 waves), normalize own col -> hb_lds
    {
        #pragma unroll
        for (int r = 0; r < 4; ++r) {
            const int tk = quad * 4 + r;
            float stot = 0.f, sstot = 0.f;
            #pragma unroll
            for (int w = 0; w < 8; ++w) {
                stot  += sln[w][0][tk];
                sstot += sln[w][1][tk];
            }
            const float mu  = stot * (1.f / 128.f);
            const float inv = rsqrtf(sstot * (1.f / 128.f) - mu * mu + 1e-5f);
            hb_lds[tk][col] = f2bf((v[r] - mu) * inv * g[col] + be[col]);
        }
    }
    __syncthreads();

    // ---- FFN1: wave covers mid-cols [wv*64, wv*64+64)
    bf16x8 hf[4];
    #pragma unroll
    for (int kk = 0; kk < 4; ++kk)
        hf[kk] = *(const bf16x8*)&hb_lds[l15][kk * 32 + quad * 8];
    #pragma unroll
    for (int nb = 0; nb < 4; ++nb) {
        const int colf = wv * 64 + nb * 16 + l15;
        f32x4 a = {0.f, 0.f, 0.f, 0.f};
        #pragma unroll
        for (int kk = 0; kk < 4; ++kk) {
            const bf16x8 wf = *(const bf16x8*)(w1 + (size_t)colf * 128 + kk * 32 + quad * 8);
            a = __builtin_amdgcn_mfma_f32_16x16x32_bf16(hf[kk], wf, a, 0, 0, 0);
        }
        const float bz = b1[colf];
        #pragma unroll
        for (int r = 0; r < 4; ++r) {
            float x = a[r] + bz;
            x = 0.5f * x * (1.f + erff(x * 0.70710678118f));
            smid[quad * 4 + r][colf] = f2bf(x);
        }
    }
    __syncthreads();

    // ---- FFN2 FULL-K (K=512): wave owns out-col group col; 2 acc chains
    f32x4 acc0 = {0.f, 0.f, 0.f, 0.f};
    f32x4 acc1 = {0.f, 0.f, 0.f, 0.f};
    #pragma unroll
    for (int kk = 0; kk < 8; ++kk) {
        const bf16x8 afA = *(const bf16x8*)&smid[l15][(2 * kk) * 32 + quad * 8];
        const bf16x8 afB = *(const bf16x8*)&smid[l15][(2 * kk + 1) * 32 + quad * 8];
        const bf16x8 wfA = *(const bf16x8*)(w2 + (size_t)col * 512 + (2 * kk) * 32 + quad * 8);
        const bf16x8 wfB = *(const bf16x8*)(w2 + (size_t)col * 512 + (2 * kk + 1) * 32 + quad * 8);
        acc0 = __builtin_amdgcn_mfma_f32_16x16x32_bf16(afA, wfA, acc0, 0, 0, 0);
        acc1 = __builtin_amdgcn_mfma_f32_16x16x32_bf16(afB, wfB, acc1, 0, 0, 0);
    }

    // ---- + b2 + out1 residual (in regs), store [B,128,N] fp32
    {
        const int b = m0 >> 12;
        const int nb0 = (m0 & 4095) + quad * 4;
        const float bz = b2[col];
        const f32x4 a = acc0 + acc1;
        f32x4 res;
        #pragma unroll
        for (int r = 0; r < 4; ++r)
            res[r] = a[r] + bz + v[r];
        *(f32x4*)&out[((size_t)(b * 128 + col)) * N_ + nb0] = res;
    }
}

// ---------------------------------------------------------------------------
extern "C" void kernel_launch(void* const* d_in, const int* in_sizes, int n_in,
                              void* d_out, int out_size, void* d_ws, size_t ws_size,
                              hipStream_t stream) {
    const float* enc   = (const float*)d_in[0];
    const float* dec   = (const float*)d_in[1];
    const float* Wq    = (const float*)d_in[2];
    const float* bq    = (const float*)d_in[3];
    const float* Wk    = (const float*)d_in[4];
    const float* bk    = (const float*)d_in[5];
    const float* Wv    = (const float*)d_in[6];
    const float* bv    = (const float*)d_in[7];
    const float* Wo    = (const float*)d_in[8];
    const float* bo    = (const float*)d_in[9];
    const float* g_enc = (const float*)d_in[10];
    const float* b_enc = (const float*)d_in[11];
    const float* g_dec = (const float*)d_in[12];
    const float* b_dec = (const float*)d_in[13];
    const float* g_out = (const float*)d_in[14];
    const float* b_out = (const float*)d_in[15];
    const float* W1    = (const float*)d_in[16];
    const float* b1    = (const float*)d_in[17];
    const float* W2    = (const float*)d_in[18];
    const float* b2    = (const float*)d_in[19];
    float* out = (float*)d_out;
    char*  W   = (char*)d_ws;

    // workspace layout (<= 13 MB, subset of prior passing footprint)
    unsigned short* wob = (unsigned short*)(W);          // 32 KB
    unsigned short* w1b = wob + 16384;                   // 128 KB
    unsigned short* w2b = w1b + 65536;                   // 128 KB (ends 288 KB)
    unsigned short* dec_lnb = (unsigned short*)(W + (2560ull << 10));   // [2.5, 4.5) MB
    unsigned short* Qh      = (unsigned short*)(W + (4608ull << 10));   // [4.5, 6.5)
    unsigned short* Kh      = (unsigned short*)(W + (6656ull << 10));   // [6.5, 8.5)
    unsigned short* Vt      = (unsigned short*)(W + (8704ull << 10));   // [8.5, 10.5)
    unsigned short* ctx     = (unsigned short*)(W + (10752ull << 10));  // 2 MB

    // QKV (+inline LN, LDS-staged bf16 weights, folded tail-weight cvt)
    qkv4_kernel<<<768, 256, 0, stream>>>(
        enc, dec, g_enc, b_enc, g_dec, b_dec, Wq, Wk, Wv, bq, bk, bv,
        Wo, W1, W2, wob, w1b, w2b, Qh, Kh, Vt, dec_lnb);

    // 512 blocks x 512 thr, XCD-affine (gid&7 == bh); in-block split combine
    attn_kernel7<<<512, 512, 0, stream>>>(Qh, Kh, Vt, ctx);

    // 512 blocks x 512 thr (8 waves), 2 blocks/CU = 4 waves/SIMD
    fused_tail7_kernel<<<512, 512, 0, stream>>>(ctx, wob, bo, dec_lnb,
                                                g_out, b_out, w1b, b1, w2b, b2, out);
}

// Round 7
// 151.111 us; speedup vs baseline: 1.0127x; 1.0127x over previous
//
#include <hip/hip_runtime.h>
#include <hip/hip_bf16.h>
#include <math.h>

#define B_ 2
#define N_ 4096          // H*W*D
#define BN_ 8192
#define NH_ 4
#define SPLIT_ 8         // attention K-split (in-block: 8 waves = 8 splits)

using bf16x8   = __attribute__((ext_vector_type(8))) __bf16;
using f32x4    = __attribute__((ext_vector_type(4))) float;
using ushortx8 = __attribute__((ext_vector_type(8))) unsigned short;

#if __has_builtin(__builtin_amdgcn_exp2f)
#define FAST_EXP2(x) __builtin_amdgcn_exp2f(x)
#else
#define FAST_EXP2(x) __expf((x) * 0.6931471805599453f)
#endif

static __device__ __forceinline__ unsigned short f2bf(float f) {
    union { __hip_bfloat16 h; unsigned short u; } c;
    c.h = __float2bfloat16(f);
    return c.u;
}
static __device__ __forceinline__ float bf2f(unsigned short u) {
    union { __hip_bfloat16 h; unsigned short u; } c;
    c.u = u;
    return __bfloat162float(c.h);
}
// pack two f32 -> two bf16 (round-biased truncate) in one v_perm_b32
static __device__ __forceinline__ unsigned int pk2bf(float lo, float hi) {
    return __builtin_amdgcn_perm(__float_as_uint(hi) + 0x8000u,
                                 __float_as_uint(lo) + 0x8000u, 0x07060302u);
}
// native packed f32->bf16 (1 VALU inst vs 3 for pk2bf); gfx950 has no builtin
static __device__ __forceinline__ unsigned int cvtpk(float lo, float hi) {
    unsigned int r;
    asm("v_cvt_pk_bf16_f32 %0, %1, %2" : "=v"(r) : "v"(lo), "v"(hi));
    return r;
}

// ---------------------------------------------------------------------------
// QKV v6 (R2-proven, unchanged): LDS-staged LN + projection with LDS-staged
// bf16 weights; float4 input staging; tail-weight conversion folded into the
// 768 main blocks (grid 768 = exactly 3 blocks/CU, single-shot).
// ---------------------------------------------------------------------------
__global__ __launch_bounds__(256)
void qkv4_kernel(const float* __restrict__ enc, const float* __restrict__ dec,
                 const float* __restrict__ g_enc, const float* __restrict__ b_enc,
                 const float* __restrict__ g_dec, const float* __restrict__ b_dec,
                 const float* __restrict__ Wq, const float* __restrict__ Wk,
                 const float* __restrict__ Wv,
                 const float* __restrict__ bq, const float* __restrict__ bk,
                 const float* __restrict__ bv,
                 const float* __restrict__ Wo, const float* __restrict__ W1,
                 const float* __restrict__ W2,
                 unsigned short* __restrict__ wo, unsigned short* __restrict__ w1,
                 unsigned short* __restrict__ w2,
                 unsigned short* __restrict__ Qh, unsigned short* __restrict__ Kh,
                 unsigned short* __restrict__ Vt,
                 unsigned short* __restrict__ dec_lnb) {
    const int t = threadIdx.x;
    __shared__ float tile[128][33];
    __shared__ float mu_s[32], inv_s[32];
    __shared__ alignas(16) unsigned short Wlds[128][136];   // 34.8 KB, pad=8
    const int z  = blockIdx.x >> 8;       // 0 Q/dec, 1 K/enc, 2 V/enc
    const int m0 = (blockIdx.x & 255) * 32;
    const int b  = m0 >> 12, n0 = m0 & 4095;
    const float* inb   = ((z == 0) ? dec : enc) + (size_t)b * 128 * N_;
    const float* gamma = (z == 0) ? g_dec : g_enc;
    const float* beta  = (z == 0) ? b_dec : b_enc;
    const float* Wb    = (z == 0) ? Wq : ((z == 1) ? Wk : Wv);

    // ---- folded tail-weight conversion: 192 elems per block (24 thr x 8)
    if (t < 24) {
        const int e = (int)blockIdx.x * 192 + t * 8;
        const float* src; unsigned short* dst; int off;
        if (e < 16384)       { src = Wo; dst = wo; off = e; }
        else if (e < 81920)  { src = W1; dst = w1; off = e - 16384; }
        else                 { src = W2; dst = w2; off = e - 81920; }
        const float4 a = *(const float4*)(src + off);
        const float4 bq4 = *(const float4*)(src + off + 4);
        uint4 p;
        p.x = pk2bf(a.x, a.y); p.y = pk2bf(a.z, a.w);
        p.z = pk2bf(bq4.x, bq4.y); p.w = pk2bf(bq4.z, bq4.w);
        *(uint4*)(dst + off) = p;
    }

    // stage input: 128 chans x 32 tokens, float4 global loads (coalesced)
    {
        const int r0 = t >> 3;            // 0..31
        const int cf = (t & 7) * 4;
        #pragma unroll
        for (int j = 0; j < 4; ++j) {
            const int r = r0 + 32 * j;
            const float4 x = *(const float4*)(inb + (size_t)r * N_ + n0 + cf);
            tile[r][cf]     = x.x; tile[r][cf + 1] = x.y;
            tile[r][cf + 2] = x.z; tile[r][cf + 3] = x.w;
        }
    }
    // stage + convert weights: 128x128 fp32 -> bf16 LDS, coalesced (2KB/instr)
    {
        #pragma unroll
        for (int i = 0; i < 8; ++i) {
            const int e   = (i * 256 + t) * 8;    // linear element, row-major [col][k]
            const int col = e >> 7, k = e & 127;
            const float4 wa = *(const float4*)(Wb + e);
            const float4 wb = *(const float4*)(Wb + e + 4);
            uint4 p;
            p.x = pk2bf(wa.x, wa.y); p.y = pk2bf(wa.z, wa.w);
            p.z = pk2bf(wb.x, wb.y); p.w = pk2bf(wb.z, wb.w);
            *(uint4*)&Wlds[col][k] = p;
        }
    }
    __syncthreads();
    // LN stats: 8 threads per token
    {
        const int tok = t >> 3;
        const int ln  = t & 7;
        float s = 0.f, ss = 0.f;
        for (int c = ln; c < 128; c += 8) {
            const float x = tile[c][tok];
            s += x; ss += x * x;
        }
        for (int m = 1; m < 8; m <<= 1) {
            s  += __shfl_xor(s, m);
            ss += __shfl_xor(ss, m);
        }
        if (ln == 0) {
            const float mu  = s * (1.f / 128.f);
            mu_s[tok]  = mu;
            inv_s[tok] = rsqrtf(ss * (1.f / 128.f) - mu * mu + 1e-5f);
        }
    }
    __syncthreads();

    const int wvx = t >> 6, lane = t & 63;
    const int l15 = lane & 15, quad = lane >> 4;
    const int tokgrp  = (wvx & 1) * 16;
    const int colbase = (wvx >> 1) * 64;
    const bool wrLN   = (z == 0) && ((wvx >> 1) == 0);
    const int tok = tokgrp + l15;
    const float mu  = mu_s[tok];
    const float inv = inv_s[tok];

    // build LN'd A-frags straight from LDS
    bf16x8 af[4];
    #pragma unroll
    for (int kk = 0; kk < 4; ++kk) {
        float y[8];
        #pragma unroll
        for (int j = 0; j < 8; ++j) {
            const int c = kk * 32 + quad * 8 + j;
            y[j] = (tile[c][tok] - mu) * inv * gamma[c] + beta[c];
        }
        union { uint4 u; bf16x8 v8; ushortx8 us; } cvt;
        cvt.u.x = pk2bf(y[0], y[1]); cvt.u.y = pk2bf(y[2], y[3]);
        cvt.u.z = pk2bf(y[4], y[5]); cvt.u.w = pk2bf(y[6], y[7]);
        af[kk] = cvt.v8;
        if (wrLN)
            *(ushortx8*)(dec_lnb + (size_t)(m0 + tok) * 128 + kk * 32 + quad * 8) = cvt.us;
    }

    const float* bias = (z == 0) ? bq : ((z == 1) ? bk : bv);
    const float sc = (z == 0) ? (0.17677669529663687f * 1.4426950408889634f) : 1.f;
    const int nbase = n0 + tokgrp + quad * 4;

    #pragma unroll
    for (int nb = 0; nb < 4; ++nb) {
        const int col = colbase + nb * 16 + l15;
        f32x4 a = {0.f, 0.f, 0.f, 0.f};
        #pragma unroll
        for (int kk = 0; kk < 4; ++kk) {
            const bf16x8 wf = *(const bf16x8*)&Wlds[col][kk * 32 + quad * 8];
            a = __builtin_amdgcn_mfma_f32_16x16x32_bf16(af[kk], wf, a, 0, 0, 0);
        }
        const int h = col >> 5, d = col & 31;
        const float bz = bias[col];
        if (z == 2) {
            ushort4 pk;
            pk.x = f2bf(a[0] + bz);
            pk.y = f2bf(a[1] + bz);
            pk.z = f2bf(a[2] + bz);
            pk.w = f2bf(a[3] + bz);
            *(ushort4*)(Vt + ((size_t)(b * NH_ + h) * 32 + d) * N_ + nbase) = pk;
        } else {
            unsigned short* dst = (z == 0) ? Qh : Kh;
            #pragma unroll
            for (int r = 0; r < 4; ++r)
                dst[((size_t)(b * NH_ + h) * N_ + nbase + r) * 32 + d] = f2bf((a[r] + bz) * sc);
        }
    }
}

// ---------------------------------------------------------------------------
// Attention v12: QK-phase VALU diet. (a) P packed with native
// v_cvt_pk_bf16_f32 (32 inst/iter vs 96 for pk2bf). (b) softmax denominator
// moved off the VALU: lacc[f] = mfma(ones, pf, lacc[f]) during PV (8 extra
// MFMA/iter replace 48 VALU adds/iter + 8 end shuffles; all D-rows equal,
// r=0 read out). (c) V loads moved after the QK phase (shorter live range,
// keeps peak VGPR under the (512,2)-enforced 128 cliff).
// ---------------------------------------------------------------------------
__global__ __launch_bounds__(512, 2)
void attn_kernel7(const unsigned short* __restrict__ Qh,
                  const unsigned short* __restrict__ Kh,
                  const unsigned short* __restrict__ Vt,
                  unsigned short* __restrict__ ctx) {
    __shared__ alignas(16) unsigned short sP[8][64][72];  // 73728 B; reused fp32 [8][64][36]
    __shared__ float ldsL[8][64];

    const int gid  = blockIdx.x;
    const int bh   = gid & 7;
    const int qblk = gid >> 3;          // 0..63
    const int t  = threadIdx.x;
    const int wvx = t >> 6, lane = t & 63;
    const int l15 = lane & 15, quad = lane >> 4;
    const int s = wvx;
    const int qw = qblk * 64;
    const size_t hbse = (size_t)bh * N_ * 32;

    bf16x8 qf[4];
    #pragma unroll
    for (int f = 0; f < 4; ++f)
        qf[f] = *(const bf16x8*)(Qh + hbse + (size_t)(qw + f * 16 + l15) * 32 + quad * 8);

    const unsigned short* Kp = Kh + hbse;
    const unsigned short* Vp = Vt + (size_t)bh * 32 * N_;

    // all-ones bf16 A-fragment for the denominator MFMA
    bf16x8 ones;
    {
        union { unsigned short u; __bf16 h; } c1; c1.u = 0x3F80;
        #pragma unroll
        for (int j = 0; j < 8; ++j) ones[j] = c1.h;
    }

    f32x4 o0[4], o1[4], lacc[4];
    #pragma unroll
    for (int f = 0; f < 4; ++f) {
        o0[f]   = f32x4{0.f, 0.f, 0.f, 0.f};
        o1[f]   = f32x4{0.f, 0.f, 0.f, 0.f};
        lacc[f] = f32x4{0.f, 0.f, 0.f, 0.f};
    }
    const f32x4 zero = {0.f, 0.f, 0.f, 0.f};

    const int kbeg = s * (N_ / SPLIT_);
    const int kend = kbeg + (N_ / SPLIT_);

    for (int k0 = kbeg; k0 < kend; k0 += 64) {
        // K fragments for THIS iter
        bf16x8 kf[4];
        #pragma unroll
        for (int c = 0; c < 4; ++c)
            kf[c] = *(const bf16x8*)(Kp + (size_t)(k0 + c * 16 + l15) * 32 + quad * 8);

        __builtin_amdgcn_s_setprio(1);
        #pragma unroll
        for (int f = 0; f < 4; ++f) {
            #pragma unroll
            for (int c = 0; c < 4; ++c) {
                const f32x4 sv = __builtin_amdgcn_mfma_f32_16x16x32_bf16(kf[c], qf[f], zero, 0, 0, 0);
                const float p0 = FAST_EXP2(sv[0]);
                const float p1 = FAST_EXP2(sv[1]);
                const float p2 = FAST_EXP2(sv[2]);
                const float p3 = FAST_EXP2(sv[3]);
                uint2 pk;
                pk.x = cvtpk(p0, p1);
                pk.y = cvtpk(p2, p3);
                *(uint2*)&sP[wvx][f * 16 + l15][c * 16 + quad * 4] = pk;
            }
        }
        __builtin_amdgcn_s_setprio(0);

        // V fragments (loaded post-QK: shorter live range)
        bf16x8 va[2], vb[2];
        #pragma unroll
        for (int s2 = 0; s2 < 2; ++s2) {
            va[s2] = *(const bf16x8*)(Vp + (size_t)l15 * N_        + k0 + s2 * 32 + quad * 8);
            vb[s2] = *(const bf16x8*)(Vp + (size_t)(16 + l15) * N_ + k0 + s2 * 32 + quad * 8);
        }

        __builtin_amdgcn_s_setprio(1);
        #pragma unroll
        for (int f = 0; f < 4; ++f) {
            #pragma unroll
            for (int s2 = 0; s2 < 2; ++s2) {
                const bf16x8 pf = *(const bf16x8*)&sP[wvx][f * 16 + l15][s2 * 32 + quad * 8];
                o0[f]   = __builtin_amdgcn_mfma_f32_16x16x32_bf16(va[s2], pf, o0[f], 0, 0, 0);
                o1[f]   = __builtin_amdgcn_mfma_f32_16x16x32_bf16(vb[s2], pf, o1[f], 0, 0, 0);
                lacc[f] = __builtin_amdgcn_mfma_f32_16x16x32_bf16(ones,   pf, lacc[f], 0, 0, 0);
            }
        }
        __builtin_amdgcn_s_setprio(0);
    }

    __syncthreads();
    float* ldsO = (float*)&sP[0][0][0];   // [8][64][36]
    #pragma unroll
    for (int f = 0; f < 4; ++f) {
        const int q = f * 16 + l15;
        float* row = ldsO + ((size_t)s * 64 + q) * 36;
        *(f32x4*)(row + quad * 4)      = o0[f];
        *(f32x4*)(row + 16 + quad * 4) = o1[f];
        if (quad == 0) ldsL[s][q] = lacc[f][0];   // all acc rows identical
    }
    __syncthreads();

    const int tok = t >> 3;
    const int d0  = (t & 7) * 4;
    f32x4 sum = {0.f, 0.f, 0.f, 0.f};
    float lsum = 0.f;
    #pragma unroll
    for (int w = 0; w < 8; ++w) {
        sum  += *(const f32x4*)(ldsO + ((size_t)w * 64 + tok) * 36 + d0);
        lsum += ldsL[w][tok];
    }
    const float inv = 1.f / lsum;
    uint2 pk;
    pk.x = pk2bf(sum[0] * inv, sum[1] * inv);
    pk.y = pk2bf(sum[2] * inv, sum[3] * inv);
    const int b = bh >> 2, h = bh & 3;
    *(uint2*)(ctx + ((size_t)(b * N_ + qw + tok)) * 128 + h * 32 + d0) = pk;
}

// ---------------------------------------------------------------------------
// Fused tail v7 (R6, kept): 512 threads / 8 waves per block, wave owns one
// 16-col output group; Wo 4 MFMA, FFN1 16 MFMA, FFN2 16 MFMA full-K.
// ---------------------------------------------------------------------------
__global__ __launch_bounds__(512)
void fused_tail7_kernel(const unsigned short* __restrict__ ctx,
                        const unsigned short* __restrict__ wo,
                        const float* __restrict__ bo,
                        const unsigned short* __restrict__ decb,
                        const float* __restrict__ g, const float* __restrict__ be,
                        const unsigned short* __restrict__ w1,
                        const float* __restrict__ b1,
                        const unsigned short* __restrict__ w2,
                        const float* __restrict__ b2,
                        float* __restrict__ out) {
    __shared__ float sln[8][2][16];
    __shared__ alignas(16) unsigned short hb_lds[16][136];
    __shared__ alignas(16) unsigned short smid[16][536];
    const int t = threadIdx.x;
    const int wv = t >> 6, lane = t & 63;
    const int l15 = lane & 15, quad = lane >> 4;
    const int m0 = blockIdx.x * 16;
    const int col = wv * 16 + l15;          // this wave's output column

    // ---- A-frags: ALL 128 chans of token m0+l15 (4 x 16B loads)
    bf16x8 af[4];
    #pragma unroll
    for (int kk = 0; kk < 4; ++kk)
        af[kk] = *(const bf16x8*)(ctx + (size_t)(m0 + l15) * 128 + kk * 32 + quad * 8);

    // ---- Wo FULL-K (K=128): 4 MFMA, 2 independent chains
    float v[4];
    {
        f32x4 a0 = {0.f, 0.f, 0.f, 0.f};
        f32x4 a1 = {0.f, 0.f, 0.f, 0.f};
        const bf16x8 w0 = *(const bf16x8*)(wo + (size_t)col * 128 + 0 * 32 + quad * 8);
        const bf16x8 w1f = *(const bf16x8*)(wo + (size_t)col * 128 + 1 * 32 + quad * 8);
        const bf16x8 w2f = *(const bf16x8*)(wo + (size_t)col * 128 + 2 * 32 + quad * 8);
        const bf16x8 w3f = *(const bf16x8*)(wo + (size_t)col * 128 + 3 * 32 + quad * 8);
        a0 = __builtin_amdgcn_mfma_f32_16x16x32_bf16(af[0], w0,  a0, 0, 0, 0);
        a1 = __builtin_amdgcn_mfma_f32_16x16x32_bf16(af[1], w1f, a1, 0, 0, 0);
        a0 = __builtin_amdgcn_mfma_f32_16x16x32_bf16(af[2], w2f, a0, 0, 0, 0);
        a1 = __builtin_amdgcn_mfma_f32_16x16x32_bf16(af[3], w3f, a1, 0, 0, 0);
        const f32x4 a = a0 + a1;
        const float bz = bo[col];
        #pragma unroll
        for (int r = 0; r < 4; ++r) {
            const int tok = m0 + quad * 4 + r;
            v[r] = a[r] + bz + bf2f(decb[(size_t)tok * 128 + col]);
        }
    }

    // ---- LN partial sums over this wave's 16 cols
    {
        float s[4], ss[4];
        #pragma unroll
        for (int r = 0; r < 4; ++r) {
            float a = v[r];
            float b = v[r] * v[r];
            for (int m = 1; m < 16; m <<= 1) {
                a += __shfl_xor(a, m);
                b += __shfl_xor(b, m);
            }
            s[r] = a; ss[r] = b;
        }
        if (l15 == 0) {
            #pragma unroll
            for (int r = 0; r < 4; ++r) {
                sln[wv][0][quad * 4 + r] = s[r];
                sln[wv][1][quad * 4 + r] = ss[r];
            }
        }
    }
    __syncthreads();

    // ---- full LN stats (sum 8 waves), normalize own col -> hb_lds
    {
        #pragma unroll
        for (int r = 0; r < 4; ++r) {
            const int tk = quad * 4 + r;
            float stot = 0.f, sstot = 0.f;
            #pragma unroll
            for (int w = 0; w < 8; ++w) {
                stot  += sln[w][0][tk];
                sstot += sln[w][1][tk];
            }
            const float mu  = stot * (1.f / 128.f);
            const float inv = rsqrtf(sstot * (1.f / 128.f) - mu * mu + 1e-5f);
            hb_lds[tk][col] = f2bf((v[r] - mu) * inv * g[col] + be[col]);
        }
    }
    __syncthreads();

    // ---- FFN1: wave covers mid-cols [wv*64, wv*64+64)
    bf16x8 hf[4];
    #pragma unroll
    for (int kk = 0; kk < 4; ++kk)
        hf[kk] = *(const bf16x8*)&hb_lds[l15][kk * 32 + quad * 8];
    #pragma unroll
    for (int nb = 0; nb < 4; ++nb) {
        const int colf = wv * 64 + nb * 16 + l15;
        f32x4 a = {0.f, 0.f, 0.f, 0.f};
        #pragma unroll
        for (int kk = 0; kk < 4; ++kk) {
            const bf16x8 wf = *(const bf16x8*)(w1 + (size_t)colf * 128 + kk * 32 + quad * 8);
            a = __builtin_amdgcn_mfma_f32_16x16x32_bf16(hf[kk], wf, a, 0, 0, 0);
        }
        const float bz = b1[colf];
        #pragma unroll
        for (int r = 0; r < 4; ++r) {
            float x = a[r] + bz;
            x = 0.5f * x * (1.f + erff(x * 0.70710678118f));
            smid[quad * 4 + r][colf] = f2bf(x);
        }
    }
    __syncthreads();

    // ---- FFN2 FULL-K (K=512): wave owns out-col group col; 2 acc chains
    f32x4 acc0 = {0.f, 0.f, 0.f, 0.f};
    f32x4 acc1 = {0.f, 0.f, 0.f, 0.f};
    #pragma unroll
    for (int kk = 0; kk < 8; ++kk) {
        const bf16x8 afA = *(const bf16x8*)&smid[l15][(2 * kk) * 32 + quad * 8];
        const bf16x8 afB = *(const bf16x8*)&smid[l15][(2 * kk + 1) * 32 + quad * 8];
        const bf16x8 wfA = *(const bf16x8*)(w2 + (size_t)col * 512 + (2 * kk) * 32 + quad * 8);
        const bf16x8 wfB = *(const bf16x8*)(w2 + (size_t)col * 512 + (2 * kk + 1) * 32 + quad * 8);
        acc0 = __builtin_amdgcn_mfma_f32_16x16x32_bf16(afA, wfA, acc0, 0, 0, 0);
        acc1 = __builtin_amdgcn_mfma_f32_16x16x32_bf16(afB, wfB, acc1, 0, 0, 0);
    }

    // ---- + b2 + out1 residual (in regs), store [B,128,N] fp32
    {
        const int b = m0 >> 12;
        const int nb0 = (m0 & 4095) + quad * 4;
        const float bz = b2[col];
        const f32x4 a = acc0 + acc1;
        f32x4 res;
        #pragma unroll
        for (int r = 0; r < 4; ++r)
            res[r] = a[r] + bz + v[r];
        *(f32x4*)&out[((size_t)(b * 128 + col)) * N_ + nb0] = res;
    }
}

// ---------------------------------------------------------------------------
extern "C" void kernel_launch(void* const* d_in, const int* in_sizes, int n_in,
                              void* d_out, int out_size, void* d_ws, size_t ws_size,
                              hipStream_t stream) {
    const float* enc   = (const float*)d_in[0];
    const float* dec   = (const float*)d_in[1];
    const float* Wq    = (const float*)d_in[2];
    const float* bq    = (const float*)d_in[3];
    const float* Wk    = (const float*)d_in[4];
    const float* bk    = (const float*)d_in[5];
    const float* Wv    = (const float*)d_in[6];
    const float* bv    = (const float*)d_in[7];
    const float* Wo    = (const float*)d_in[8];
    const float* bo    = (const float*)d_in[9];
    const float* g_enc = (const float*)d_in[10];
    const float* b_enc = (const float*)d_in[11];
    const float* g_dec = (const float*)d_in[12];
    const float* b_dec = (const float*)d_in[13];
    const float* g_out = (const float*)d_in[14];
    const float* b_out = (const float*)d_in[15];
    const float* W1    = (const float*)d_in[16];
    const float* b1    = (const float*)d_in[17];
    const float* W2    = (const float*)d_in[18];
    const float* b2    = (const float*)d_in[19];
    float* out = (float*)d_out;
    char*  W   = (char*)d_ws;

    // workspace layout (<= 13 MB, subset of prior passing footprint)
    unsigned short* wob = (unsigned short*)(W);          // 32 KB
    unsigned short* w1b = wob + 16384;                   // 128 KB
    unsigned short* w2b = w1b + 65536;                   // 128 KB (ends 288 KB)
    unsigned short* dec_lnb = (unsigned short*)(W + (2560ull << 10));   // [2.5, 4.5) MB
    unsigned short* Qh      = (unsigned short*)(W + (4608ull << 10));   // [4.5, 6.5)
    unsigned short* Kh      = (unsigned short*)(W + (6656ull << 10));   // [6.5, 8.5)
    unsigned short* Vt      = (unsigned short*)(W + (8704ull << 10));   // [8.5, 10.5)
    unsigned short* ctx     = (unsigned short*)(W + (10752ull << 10));  // 2 MB

    // QKV (+inline LN, LDS-staged bf16 weights, folded tail-weight cvt)
    qkv4_kernel<<<768, 256, 0, stream>>>(
        enc, dec, g_enc, b_enc, g_dec, b_dec, Wq, Wk, Wv, bq, bk, bv,
        Wo, W1, W2, wob, w1b, w2b, Qh, Kh, Vt, dec_lnb);

    // 512 blocks x 512 thr, XCD-affine (gid&7 == bh); in-block split combine
    attn_kernel7<<<512, 512, 0, stream>>>(Qh, Kh, Vt, ctx);

    // 512 blocks x 512 thr (8 waves), 2 blocks/CU = 4 waves/SIMD
    fused_tail7_kernel<<<512, 512, 0, stream>>>(ctx, wob, bo, dec_lnb,
                                                g_out, b_out, w1b, b1, w2b, b2, out);
}

// Round 8
// 150.284 us; speedup vs baseline: 1.0182x; 1.0055x over previous
//
#include <hip/hip_runtime.h>
#include <hip/hip_bf16.h>
#include <math.h>

#define B_ 2
#define N_ 4096          // H*W*D
#define BN_ 8192
#define NH_ 4
#define SPLIT_ 8         // attention K-split (in-block: 8 waves = 8 splits)

using bf16x8   = __attribute__((ext_vector_type(8))) __bf16;
using f32x4    = __attribute__((ext_vector_type(4))) float;
using ushortx8 = __attribute__((ext_vector_type(8))) unsigned short;

#if __has_builtin(__builtin_amdgcn_exp2f)
#define FAST_EXP2(x) __builtin_amdgcn_exp2f(x)
#else
#define FAST_EXP2(x) __expf((x) * 0.6931471805599453f)
#endif

static __device__ __forceinline__ unsigned short f2bf(float f) {
    union { __hip_bfloat16 h; unsigned short u; } c;
    c.h = __float2bfloat16(f);
    return c.u;
}
static __device__ __forceinline__ float bf2f(unsigned short u) {
    union { __hip_bfloat16 h; unsigned short u; } c;
    c.u = u;
    return __bfloat162float(c.h);
}
// native packed f32->bf16 (1 VALU inst); gfx950 has no builtin -> inline asm
static __device__ __forceinline__ unsigned int cvtpk(float lo, float hi) {
    unsigned int r;
    asm("v_cvt_pk_bf16_f32 %0, %1, %2" : "=v"(r) : "v"(lo), "v"(hi));
    return r;
}

// ---------------------------------------------------------------------------
// QKV v7: as R6 but ALL fp32->bf16 pair conversions use the native
// v_cvt_pk_bf16_f32 (1 inst vs 3 for the perm-based pack): weight staging
// (32 pairs/thr), LN A-frags (16), folded tail-weight cvt (4) -> ~200
// cyc/thread VALU saved.
// ---------------------------------------------------------------------------
__global__ __launch_bounds__(256)
void qkv4_kernel(const float* __restrict__ enc, const float* __restrict__ dec,
                 const float* __restrict__ g_enc, const float* __restrict__ b_enc,
                 const float* __restrict__ g_dec, const float* __restrict__ b_dec,
                 const float* __restrict__ Wq, const float* __restrict__ Wk,
                 const float* __restrict__ Wv,
                 const float* __restrict__ bq, const float* __restrict__ bk,
                 const float* __restrict__ bv,
                 const float* __restrict__ Wo, const float* __restrict__ W1,
                 const float* __restrict__ W2,
                 unsigned short* __restrict__ wo, unsigned short* __restrict__ w1,
                 unsigned short* __restrict__ w2,
                 unsigned short* __restrict__ Qh, unsigned short* __restrict__ Kh,
                 unsigned short* __restrict__ Vt,
                 unsigned short* __restrict__ dec_lnb) {
    const int t = threadIdx.x;
    __shared__ float tile[128][33];
    __shared__ float mu_s[32], inv_s[32];
    __shared__ alignas(16) unsigned short Wlds[128][136];   // 34.8 KB, pad=8
    const int z  = blockIdx.x >> 8;       // 0 Q/dec, 1 K/enc, 2 V/enc
    const int m0 = (blockIdx.x & 255) * 32;
    const int b  = m0 >> 12, n0 = m0 & 4095;
    const float* inb   = ((z == 0) ? dec : enc) + (size_t)b * 128 * N_;
    const float* gamma = (z == 0) ? g_dec : g_enc;
    const float* beta  = (z == 0) ? b_dec : b_enc;
    const float* Wb    = (z == 0) ? Wq : ((z == 1) ? Wk : Wv);

    // ---- folded tail-weight conversion: 192 elems per block (24 thr x 8)
    if (t < 24) {
        const int e = (int)blockIdx.x * 192 + t * 8;
        const float* src; unsigned short* dst; int off;
        if (e < 16384)       { src = Wo; dst = wo; off = e; }
        else if (e < 81920)  { src = W1; dst = w1; off = e - 16384; }
        else                 { src = W2; dst = w2; off = e - 81920; }
        const float4 a = *(const float4*)(src + off);
        const float4 bq4 = *(const float4*)(src + off + 4);
        uint4 p;
        p.x = cvtpk(a.x, a.y); p.y = cvtpk(a.z, a.w);
        p.z = cvtpk(bq4.x, bq4.y); p.w = cvtpk(bq4.z, bq4.w);
        *(uint4*)(dst + off) = p;
    }

    // stage input: 128 chans x 32 tokens, float4 global loads (coalesced)
    {
        const int r0 = t >> 3;            // 0..31
        const int cf = (t & 7) * 4;
        #pragma unroll
        for (int j = 0; j < 4; ++j) {
            const int r = r0 + 32 * j;
            const float4 x = *(const float4*)(inb + (size_t)r * N_ + n0 + cf);
            tile[r][cf]     = x.x; tile[r][cf + 1] = x.y;
            tile[r][cf + 2] = x.z; tile[r][cf + 3] = x.w;
        }
    }
    // stage + convert weights: 128x128 fp32 -> bf16 LDS, coalesced (2KB/instr)
    {
        #pragma unroll
        for (int i = 0; i < 8; ++i) {
            const int e   = (i * 256 + t) * 8;    // linear element, row-major [col][k]
            const int col = e >> 7, k = e & 127;
            const float4 wa = *(const float4*)(Wb + e);
            const float4 wb = *(const float4*)(Wb + e + 4);
            uint4 p;
            p.x = cvtpk(wa.x, wa.y); p.y = cvtpk(wa.z, wa.w);
            p.z = cvtpk(wb.x, wb.y); p.w = cvtpk(wb.z, wb.w);
            *(uint4*)&Wlds[col][k] = p;
        }
    }
    __syncthreads();
    // LN stats: 8 threads per token
    {
        const int tok = t >> 3;
        const int ln  = t & 7;
        float s = 0.f, ss = 0.f;
        for (int c = ln; c < 128; c += 8) {
            const float x = tile[c][tok];
            s += x; ss += x * x;
        }
        for (int m = 1; m < 8; m <<= 1) {
            s  += __shfl_xor(s, m);
            ss += __shfl_xor(ss, m);
        }
        if (ln == 0) {
            const float mu  = s * (1.f / 128.f);
            mu_s[tok]  = mu;
            inv_s[tok] = rsqrtf(ss * (1.f / 128.f) - mu * mu + 1e-5f);
        }
    }
    __syncthreads();

    const int wvx = t >> 6, lane = t & 63;
    const int l15 = lane & 15, quad = lane >> 4;
    const int tokgrp  = (wvx & 1) * 16;
    const int colbase = (wvx >> 1) * 64;
    const bool wrLN   = (z == 0) && ((wvx >> 1) == 0);
    const int tok = tokgrp + l15;
    const float mu  = mu_s[tok];
    const float inv = inv_s[tok];

    // build LN'd A-frags straight from LDS
    bf16x8 af[4];
    #pragma unroll
    for (int kk = 0; kk < 4; ++kk) {
        float y[8];
        #pragma unroll
        for (int j = 0; j < 8; ++j) {
            const int c = kk * 32 + quad * 8 + j;
            y[j] = (tile[c][tok] - mu) * inv * gamma[c] + beta[c];
        }
        union { uint4 u; bf16x8 v8; ushortx8 us; } cvt;
        cvt.u.x = cvtpk(y[0], y[1]); cvt.u.y = cvtpk(y[2], y[3]);
        cvt.u.z = cvtpk(y[4], y[5]); cvt.u.w = cvtpk(y[6], y[7]);
        af[kk] = cvt.v8;
        if (wrLN)
            *(ushortx8*)(dec_lnb + (size_t)(m0 + tok) * 128 + kk * 32 + quad * 8) = cvt.us;
    }

    const float* bias = (z == 0) ? bq : ((z == 1) ? bk : bv);
    const float sc = (z == 0) ? (0.17677669529663687f * 1.4426950408889634f) : 1.f;
    const int nbase = n0 + tokgrp + quad * 4;

    #pragma unroll
    for (int nb = 0; nb < 4; ++nb) {
        const int col = colbase + nb * 16 + l15;
        f32x4 a = {0.f, 0.f, 0.f, 0.f};
        #pragma unroll
        for (int kk = 0; kk < 4; ++kk) {
            const bf16x8 wf = *(const bf16x8*)&Wlds[col][kk * 32 + quad * 8];
            a = __builtin_amdgcn_mfma_f32_16x16x32_bf16(af[kk], wf, a, 0, 0, 0);
        }
        const int h = col >> 5, d = col & 31;
        const float bz = bias[col];
        if (z == 2) {
            ushort4 pk;
            pk.x = f2bf(a[0] + bz);
            pk.y = f2bf(a[1] + bz);
            pk.z = f2bf(a[2] + bz);
            pk.w = f2bf(a[3] + bz);
            *(ushort4*)(Vt + ((size_t)(b * NH_ + h) * 32 + d) * N_ + nbase) = pk;
        } else {
            unsigned short* dst = (z == 0) ? Qh : Kh;
            #pragma unroll
            for (int r = 0; r < 4; ++r)
                dst[((size_t)(b * NH_ + h) * N_ + nbase + r) * 32 + d] = f2bf((a[r] + bz) * sc);
        }
    }
}

// ---------------------------------------------------------------------------
// Attention v13: as v12 plus fine QK/PV interleave: QK(c0,c1) -> PV(s2=0)
// -> QK(c2,c3) -> PV(s2=1). PV half 1 only needs sP cols 0..31 (written by
// c0,c1), so its lgkmcnt wait is shorter and the second exp burst overlaps
// PV-half-1's ds_read+MFMA latency. Identical arithmetic, reordered.
// ---------------------------------------------------------------------------
__global__ __launch_bounds__(512, 2)
void attn_kernel7(const unsigned short* __restrict__ Qh,
                  const unsigned short* __restrict__ Kh,
                  const unsigned short* __restrict__ Vt,
                  unsigned short* __restrict__ ctx) {
    __shared__ alignas(16) unsigned short sP[8][64][72];  // 73728 B; reused fp32 [8][64][36]
    __shared__ float ldsL[8][64];

    const int gid  = blockIdx.x;
    const int bh   = gid & 7;
    const int qblk = gid >> 3;          // 0..63
    const int t  = threadIdx.x;
    const int wvx = t >> 6, lane = t & 63;
    const int l15 = lane & 15, quad = lane >> 4;
    const int s = wvx;
    const int qw = qblk * 64;
    const size_t hbse = (size_t)bh * N_ * 32;

    bf16x8 qf[4];
    #pragma unroll
    for (int f = 0; f < 4; ++f)
        qf[f] = *(const bf16x8*)(Qh + hbse + (size_t)(qw + f * 16 + l15) * 32 + quad * 8);

    const unsigned short* Kp = Kh + hbse;
    const unsigned short* Vp = Vt + (size_t)bh * 32 * N_;

    // all-ones bf16 A-fragment for the denominator MFMA
    bf16x8 ones;
    {
        union { unsigned short u; __bf16 h; } c1; c1.u = 0x3F80;
        #pragma unroll
        for (int j = 0; j < 8; ++j) ones[j] = c1.h;
    }

    f32x4 o0[4], o1[4], lacc[4];
    #pragma unroll
    for (int f = 0; f < 4; ++f) {
        o0[f]   = f32x4{0.f, 0.f, 0.f, 0.f};
        o1[f]   = f32x4{0.f, 0.f, 0.f, 0.f};
        lacc[f] = f32x4{0.f, 0.f, 0.f, 0.f};
    }
    const f32x4 zero = {0.f, 0.f, 0.f, 0.f};

    const int kbeg = s * (N_ / SPLIT_);
    const int kend = kbeg + (N_ / SPLIT_);

    for (int k0 = kbeg; k0 < kend; k0 += 64) {
        // K fragments for THIS iter
        bf16x8 kf[4];
        #pragma unroll
        for (int c = 0; c < 4; ++c)
            kf[c] = *(const bf16x8*)(Kp + (size_t)(k0 + c * 16 + l15) * 32 + quad * 8);

        __builtin_amdgcn_s_setprio(1);
        // ---- QK half 1: c = 0,1  (fills sP cols 0..31)
        #pragma unroll
        for (int f = 0; f < 4; ++f) {
            #pragma unroll
            for (int c = 0; c < 2; ++c) {
                const f32x4 sv = __builtin_amdgcn_mfma_f32_16x16x32_bf16(kf[c], qf[f], zero, 0, 0, 0);
                const float p0 = FAST_EXP2(sv[0]);
                const float p1 = FAST_EXP2(sv[1]);
                const float p2 = FAST_EXP2(sv[2]);
                const float p3 = FAST_EXP2(sv[3]);
                uint2 pk;
                pk.x = cvtpk(p0, p1);
                pk.y = cvtpk(p2, p3);
                *(uint2*)&sP[wvx][f * 16 + l15][c * 16 + quad * 4] = pk;
            }
        }
        __builtin_amdgcn_s_setprio(0);

        // V fragments
        bf16x8 va[2], vb[2];
        #pragma unroll
        for (int s2 = 0; s2 < 2; ++s2) {
            va[s2] = *(const bf16x8*)(Vp + (size_t)l15 * N_        + k0 + s2 * 32 + quad * 8);
            vb[s2] = *(const bf16x8*)(Vp + (size_t)(16 + l15) * N_ + k0 + s2 * 32 + quad * 8);
        }

        __builtin_amdgcn_s_setprio(1);
        // ---- PV half 1 (s2=0, reads sP cols 0..31)
        #pragma unroll
        for (int f = 0; f < 4; ++f) {
            const bf16x8 pf = *(const bf16x8*)&sP[wvx][f * 16 + l15][quad * 8];
            o0[f]   = __builtin_amdgcn_mfma_f32_16x16x32_bf16(va[0], pf, o0[f], 0, 0, 0);
            o1[f]   = __builtin_amdgcn_mfma_f32_16x16x32_bf16(vb[0], pf, o1[f], 0, 0, 0);
            lacc[f] = __builtin_amdgcn_mfma_f32_16x16x32_bf16(ones,  pf, lacc[f], 0, 0, 0);
        }
        // ---- QK half 2: c = 2,3  (fills sP cols 32..63, overlaps PV1 latency)
        #pragma unroll
        for (int f = 0; f < 4; ++f) {
            #pragma unroll
            for (int c = 2; c < 4; ++c) {
                const f32x4 sv = __builtin_amdgcn_mfma_f32_16x16x32_bf16(kf[c], qf[f], zero, 0, 0, 0);
                const float p0 = FAST_EXP2(sv[0]);
                const float p1 = FAST_EXP2(sv[1]);
                const float p2 = FAST_EXP2(sv[2]);
                const float p3 = FAST_EXP2(sv[3]);
                uint2 pk;
                pk.x = cvtpk(p0, p1);
                pk.y = cvtpk(p2, p3);
                *(uint2*)&sP[wvx][f * 16 + l15][c * 16 + quad * 4] = pk;
            }
        }
        // ---- PV half 2 (s2=1, reads sP cols 32..63)
        #pragma unroll
        for (int f = 0; f < 4; ++f) {
            const bf16x8 pf = *(const bf16x8*)&sP[wvx][f * 16 + l15][32 + quad * 8];
            o0[f]   = __builtin_amdgcn_mfma_f32_16x16x32_bf16(va[1], pf, o0[f], 0, 0, 0);
            o1[f]   = __builtin_amdgcn_mfma_f32_16x16x32_bf16(vb[1], pf, o1[f], 0, 0, 0);
            lacc[f] = __builtin_amdgcn_mfma_f32_16x16x32_bf16(ones,  pf, lacc[f], 0, 0, 0);
        }
        __builtin_amdgcn_s_setprio(0);
    }

    __syncthreads();
    float* ldsO = (float*)&sP[0][0][0];   // [8][64][36]
    #pragma unroll
    for (int f = 0; f < 4; ++f) {
        const int q = f * 16 + l15;
        float* row = ldsO + ((size_t)s * 64 + q) * 36;
        *(f32x4*)(row + quad * 4)      = o0[f];
        *(f32x4*)(row + 16 + quad * 4) = o1[f];
        if (quad == 0) ldsL[s][q] = lacc[f][0];   // all acc rows identical
    }
    __syncthreads();

    const int tok = t >> 3;
    const int d0  = (t & 7) * 4;
    f32x4 sum = {0.f, 0.f, 0.f, 0.f};
    float lsum = 0.f;
    #pragma unroll
    for (int w = 0; w < 8; ++w) {
        sum  += *(const f32x4*)(ldsO + ((size_t)w * 64 + tok) * 36 + d0);
        lsum += ldsL[w][tok];
    }
    const float inv = 1.f / lsum;
    uint2 pk;
    pk.x = cvtpk(sum[0] * inv, sum[1] * inv);
    pk.y = cvtpk(sum[2] * inv, sum[3] * inv);
    const int b = bh >> 2, h = bh & 3;
    *(uint2*)(ctx + ((size_t)(b * N_ + qw + tok)) * 128 + h * 32 + d0) = pk;
}

// ---------------------------------------------------------------------------
// Fused tail v8: as v7 plus cross-barrier weight prefetch — FFN1's nb=0
// fragments are loaded before the LN barriers (hide ~500cy VMEM under LN),
// FFN2's kk=0 fragments before its barrier (hide under FFN1 epilogue).
// ---------------------------------------------------------------------------
__global__ __launch_bounds__(512)
void fused_tail7_kernel(const unsigned short* __restrict__ ctx,
                        const unsigned short* __restrict__ wo,
                        const float* __restrict__ bo,
                        const unsigned short* __restrict__ decb,
                        const float* __restrict__ g, const float* __restrict__ be,
                        const unsigned short* __restrict__ w1,
                        const float* __restrict__ b1,
                        const unsigned short* __restrict__ w2,
                        const float* __restrict__ b2,
                        float* __restrict__ out) {
    __shared__ float sln[8][2][16];
    __shared__ alignas(16) unsigned short hb_lds[16][136];
    __shared__ alignas(16) unsigned short smid[16][536];
    const int t = threadIdx.x;
    const int wv = t >> 6, lane = t & 63;
    const int l15 = lane & 15, quad = lane >> 4;
    const int m0 = blockIdx.x * 16;
    const int col = wv * 16 + l15;          // this wave's output column

    // ---- A-frags: ALL 128 chans of token m0+l15 (4 x 16B loads)
    bf16x8 af[4];
    #pragma unroll
    for (int kk = 0; kk < 4; ++kk)
        af[kk] = *(const bf16x8*)(ctx + (size_t)(m0 + l15) * 128 + kk * 32 + quad * 8);

    // ---- Wo FULL-K (K=128): 4 MFMA, 2 independent chains
    float v[4];
    {
        f32x4 a0 = {0.f, 0.f, 0.f, 0.f};
        f32x4 a1 = {0.f, 0.f, 0.f, 0.f};
        const bf16x8 w0 = *(const bf16x8*)(wo + (size_t)col * 128 + 0 * 32 + quad * 8);
        const bf16x8 w1f = *(const bf16x8*)(wo + (size_t)col * 128 + 1 * 32 + quad * 8);
        const bf16x8 w2f = *(const bf16x8*)(wo + (size_t)col * 128 + 2 * 32 + quad * 8);
        const bf16x8 w3f = *(const bf16x8*)(wo + (size_t)col * 128 + 3 * 32 + quad * 8);
        a0 = __builtin_amdgcn_mfma_f32_16x16x32_bf16(af[0], w0,  a0, 0, 0, 0);
        a1 = __builtin_amdgcn_mfma_f32_16x16x32_bf16(af[1], w1f, a1, 0, 0, 0);
        a0 = __builtin_amdgcn_mfma_f32_16x16x32_bf16(af[2], w2f, a0, 0, 0, 0);
        a1 = __builtin_amdgcn_mfma_f32_16x16x32_bf16(af[3], w3f, a1, 0, 0, 0);
        const f32x4 a = a0 + a1;
        const float bz = bo[col];
        #pragma unroll
        for (int r = 0; r < 4; ++r) {
            const int tok = m0 + quad * 4 + r;
            v[r] = a[r] + bz + bf2f(decb[(size_t)tok * 128 + col]);
        }
    }

    // ---- prefetch FFN1 nb=0 weight fragments (independent of LN barriers)
    bf16x8 w1p[4];
    {
        const int colf = wv * 64 + l15;
        #pragma unroll
        for (int kk = 0; kk < 4; ++kk)
            w1p[kk] = *(const bf16x8*)(w1 + (size_t)colf * 128 + kk * 32 + quad * 8);
    }

    // ---- LN partial sums over this wave's 16 cols
    {
        float s[4], ss[4];
        #pragma unroll
        for (int r = 0; r < 4; ++r) {
            float a = v[r];
            float b = v[r] * v[r];
            for (int m = 1; m < 16; m <<= 1) {
                a += __shfl_xor(a, m);
                b += __shfl_xor(b, m);
            }
            s[r] = a; ss[r] = b;
        }
        if (l15 == 0) {
            #pragma unroll
            for (int r = 0; r < 4; ++r) {
                sln[wv][0][quad * 4 + r] = s[r];
                sln[wv][1][quad * 4 + r] = ss[r];
            }
        }
    }
    __syncthreads();

    // ---- full LN stats (sum 8 waves), normalize own col -> hb_lds
    {
        #pragma unroll
        for (int r = 0; r < 4; ++r) {
            const int tk = quad * 4 + r;
            float stot = 0.f, sstot = 0.f;
            #pragma unroll
            for (int w = 0; w < 8; ++w) {
                stot  += sln[w][0][tk];
                sstot += sln[w][1][tk];
            }
            const float mu  = stot * (1.f / 128.f);
            const float inv = rsqrtf(sstot * (1.f / 128.f) - mu * mu + 1e-5f);
            hb_lds[tk][col] = f2bf((v[r] - mu) * inv * g[col] + be[col]);
        }
    }
    __syncthreads();

    // ---- FFN1: wave covers mid-cols [wv*64, wv*64+64); nb=0 uses prefetch
    bf16x8 hf[4];
    #pragma unroll
    for (int kk = 0; kk < 4; ++kk)
        hf[kk] = *(const bf16x8*)&hb_lds[l15][kk * 32 + quad * 8];
    #pragma unroll
    for (int nb = 0; nb < 4; ++nb) {
        const int colf = wv * 64 + nb * 16 + l15;
        f32x4 a = {0.f, 0.f, 0.f, 0.f};
        #pragma unroll
        for (int kk = 0; kk < 4; ++kk) {
            const bf16x8 wf = (nb == 0) ? w1p[kk]
                : *(const bf16x8*)(w1 + (size_t)colf * 128 + kk * 32 + quad * 8);
            a = __builtin_amdgcn_mfma_f32_16x16x32_bf16(hf[kk], wf, a, 0, 0, 0);
        }
        const float bz = b1[colf];
        #pragma unroll
        for (int r = 0; r < 4; ++r) {
            float x = a[r] + bz;
            x = 0.5f * x * (1.f + erff(x * 0.70710678118f));
            smid[quad * 4 + r][colf] = f2bf(x);
        }
    }

    // ---- prefetch FFN2 kk=0 weight fragments before the barrier
    bf16x8 w2pA = *(const bf16x8*)(w2 + (size_t)col * 512 + 0 * 32 + quad * 8);
    bf16x8 w2pB = *(const bf16x8*)(w2 + (size_t)col * 512 + 1 * 32 + quad * 8);
    __syncthreads();

    // ---- FFN2 FULL-K (K=512): wave owns out-col group col; 2 acc chains
    f32x4 acc0 = {0.f, 0.f, 0.f, 0.f};
    f32x4 acc1 = {0.f, 0.f, 0.f, 0.f};
    #pragma unroll
    for (int kk = 0; kk < 8; ++kk) {
        const bf16x8 afA = *(const bf16x8*)&smid[l15][(2 * kk) * 32 + quad * 8];
        const bf16x8 afB = *(const bf16x8*)&smid[l15][(2 * kk + 1) * 32 + quad * 8];
        const bf16x8 wfA = (kk == 0) ? w2pA
            : *(const bf16x8*)(w2 + (size_t)col * 512 + (2 * kk) * 32 + quad * 8);
        const bf16x8 wfB = (kk == 0) ? w2pB
            : *(const bf16x8*)(w2 + (size_t)col * 512 + (2 * kk + 1) * 32 + quad * 8);
        acc0 = __builtin_amdgcn_mfma_f32_16x16x32_bf16(afA, wfA, acc0, 0, 0, 0);
        acc1 = __builtin_amdgcn_mfma_f32_16x16x32_bf16(afB, wfB, acc1, 0, 0, 0);
    }

    // ---- + b2 + out1 residual (in regs), store [B,128,N] fp32
    {
        const int b = m0 >> 12;
        const int nb0 = (m0 & 4095) + quad * 4;
        const float bz = b2[col];
        const f32x4 a = acc0 + acc1;
        f32x4 res;
        #pragma unroll
        for (int r = 0; r < 4; ++r)
            res[r] = a[r] + bz + v[r];
        *(f32x4*)&out[((size_t)(b * 128 + col)) * N_ + nb0] = res;
    }
}

// ---------------------------------------------------------------------------
extern "C" void kernel_launch(void* const* d_in, const int* in_sizes, int n_in,
                              void* d_out, int out_size, void* d_ws, size_t ws_size,
                              hipStream_t stream) {
    const float* enc   = (const float*)d_in[0];
    const float* dec   = (const float*)d_in[1];
    const float* Wq    = (const float*)d_in[2];
    const float* bq    = (const float*)d_in[3];
    const float* Wk    = (const float*)d_in[4];
    const float* bk    = (const float*)d_in[5];
    const float* Wv    = (const float*)d_in[6];
    const float* bv    = (const float*)d_in[7];
    const float* Wo    = (const float*)d_in[8];
    const float* bo    = (const float*)d_in[9];
    const float* g_enc = (const float*)d_in[10];
    const float* b_enc = (const float*)d_in[11];
    const float* g_dec = (const float*)d_in[12];
    const float* b_dec = (const float*)d_in[13];
    const float* g_out = (const float*)d_in[14];
    const float* b_out = (const float*)d_in[15];
    const float* W1    = (const float*)d_in[16];
    const float* b1    = (const float*)d_in[17];
    const float* W2    = (const float*)d_in[18];
    const float* b2    = (const float*)d_in[19];
    float* out = (float*)d_out;
    char*  W   = (char*)d_ws;

    // workspace layout (<= 13 MB, subset of prior passing footprint)
    unsigned short* wob = (unsigned short*)(W);          // 32 KB
    unsigned short* w1b = wob + 16384;                   // 128 KB
    unsigned short* w2b = w1b + 65536;                   // 128 KB (ends 288 KB)
    unsigned short* dec_lnb = (unsigned short*)(W + (2560ull << 10));   // [2.5, 4.5) MB
    unsigned short* Qh      = (unsigned short*)(W + (4608ull << 10));   // [4.5, 6.5)
    unsigned short* Kh      = (unsigned short*)(W + (6656ull << 10));   // [6.5, 8.5)
    unsigned short* Vt      = (unsigned short*)(W + (8704ull << 10));   // [8.5, 10.5)
    unsigned short* ctx     = (unsigned short*)(W + (10752ull << 10));  // 2 MB

    // QKV (+inline LN, LDS-staged bf16 weights, folded tail-weight cvt)
    qkv4_kernel<<<768, 256, 0, stream>>>(
        enc, dec, g_enc, b_enc, g_dec, b_dec, Wq, Wk, Wv, bq, bk, bv,
        Wo, W1, W2, wob, w1b, w2b, Qh, Kh, Vt, dec_lnb);

    // 512 blocks x 512 thr, XCD-affine (gid&7 == bh); in-block split combine
    attn_kernel7<<<512, 512, 0, stream>>>(Qh, Kh, Vt, ctx);

    // 512 blocks x 512 thr (8 waves), 2 blocks/CU = 4 waves/SIMD
    fused_tail7_kernel<<<512, 512, 0, stream>>>(ctx, wob, bo, dec_lnb,
                                                g_out, b_out, w1b, b1, w2b, b2, out);
}